// Round 1
// baseline (1168.997 us; speedup 1.0000x reference)
//
#include <hip/hip_runtime.h>
#include <math.h>

#define N_ATOMS 50000
#define D 32
#define E_EDGES 300000
#define BD 16
#define NCH 17              // BD + 1 bias channel
#define QW (NCH * D)        // 544
#define TILE 16
#define NTILES ((N_ATOMS + TILE - 1) / TILE)   // 3125
#define SCAN_BLOCKS ((N_ATOMS + 255) / 256)    // 196

__device__ __forceinline__ float sigmoidf_(float x) {
    return 1.0f / (1.0f + __expf(-x));
}

// ---------- precompute kernels (once per launch) ----------

// WT[s][i] with s = b*32 + j ; channel b=16 is Bm (bias.reshape(D,D))
__global__ void k_build_wt(const float* __restrict__ kern,
                           const float* __restrict__ bias,
                           float* __restrict__ WT) {
    int idx = blockIdx.x * 256 + threadIdx.x;
    if (idx >= NCH * D * D) return;
    int i = idx & 31;
    int s = idx >> 5;          // b*32 + j
    int b = s >> 5, j = s & 31;
    float v = (b < BD) ? kern[b * (D * D) + i * D + j] : bias[i * D + j];
    WT[s * D + i] = v;
}

__global__ void k_hist(const int* __restrict__ pair, int* __restrict__ deg) {
    int e = blockIdx.x * 256 + threadIdx.x;
    if (e < E_EDGES) atomicAdd(&deg[pair[2 * e]], 1);
}

__global__ void k_scan1(const int* __restrict__ deg, int* __restrict__ offs,
                        int* __restrict__ bsums) {
    __shared__ int sm[256];
    int t = threadIdx.x, gid = blockIdx.x * 256 + t;
    int v = (gid < N_ATOMS) ? deg[gid] : 0;
    sm[t] = v;
    __syncthreads();
    for (int off = 1; off < 256; off <<= 1) {
        int x = (t >= off) ? sm[t - off] : 0;
        __syncthreads();
        sm[t] += x;
        __syncthreads();
    }
    if (gid < N_ATOMS) offs[gid] = sm[t] - v;   // exclusive within block
    if (t == 255) bsums[blockIdx.x] = sm[255];
}

__global__ void k_scan2(const int* __restrict__ bsums, int* __restrict__ boffs, int nb) {
    __shared__ int sm[256];
    int t = threadIdx.x;
    int v = (t < nb) ? bsums[t] : 0;
    sm[t] = v;
    __syncthreads();
    for (int off = 1; off < 256; off <<= 1) {
        int x = (t >= off) ? sm[t - off] : 0;
        __syncthreads();
        sm[t] += x;
        __syncthreads();
    }
    if (t < nb) boffs[t] = sm[t] - v;
}

__global__ void k_scan3(int* __restrict__ offs, const int* __restrict__ boffs) {
    int gid = blockIdx.x * 256 + threadIdx.x;
    if (gid < N_ATOMS) offs[gid] += boffs[blockIdx.x];
}

__global__ void k_scatter(const int* __restrict__ pair, const int* __restrict__ offs,
                          int* __restrict__ cursor, int* __restrict__ ssrc,
                          int* __restrict__ seid) {
    int e = blockIdx.x * 256 + threadIdx.x;
    if (e >= E_EDGES) return;
    int d = pair[2 * e], s = pair[2 * e + 1];
    int pos = offs[d] + atomicAdd(&cursor[d], 1);
    ssrc[pos] = s;
    seid[pos] = e;
}

// ---------- fused per-step kernel ----------
// P1: per wave, per node: q[b*32+j] = sum_edges bond_ext[e,b]*h[src,j]  (regs -> LDS)
// P2: agg[r][i] = sum_s WT[s][i]*q[r][s]   (16-node tile, WT streamed from global)
// P3: GRU cell fused, h_out written
__global__ __launch_bounds__(256, 2)
void k_step(const float* __restrict__ h_in, float* __restrict__ h_out,
            const float* __restrict__ bond, const float* __restrict__ WT,
            const int* __restrict__ offs, const int* __restrict__ deg,
            const int* __restrict__ ssrc, const int* __restrict__ seid,
            const float* __restrict__ Wih, const float* __restrict__ Whh,
            const float* __restrict__ bih, const float* __restrict__ bhh) {
    __shared__ float q_lds[TILE][QW];        // 34816 B
    __shared__ float agg_lds[TILE][D + 1];   // 2112 B (pad -> conflict-free)
    __shared__ float h_tile[TILE][D + 1];    // 2112 B
    __shared__ float Wih_s[96][33];          // 12672 B
    __shared__ float Whh_s[96][33];          // 12672 B
    __shared__ float bih_s[96], bhh_s[96];   // 768 B

    const int t = threadIdx.x;

    // stage GRU weights once per block
    for (int idx = t; idx < 96 * 32; idx += 256) {
        int o = idx >> 5, j = idx & 31;
        Wih_s[o][j] = Wih[idx];
        Whh_s[o][j] = Whh[idx];
    }
    if (t < 96) { bih_s[t] = bih[t]; bhh_s[t] = bhh[t]; }
    __syncthreads();

    const int w = t >> 6;        // wave id 0..3
    const int l = t & 63;        // lane
    const int li = l & 31;

    for (int tile = blockIdx.x; tile < NTILES; tile += gridDim.x) {
        const int base = tile * TILE;

        // ---- phase 1: build q for 16 nodes (4 nodes per wave, serial edges)
        for (int rr = 0; rr < 4; ++rr) {
            const int r = rr * 4 + w;
            const int n = base + r;
            float q[9];
#pragma unroll
            for (int k = 0; k < 9; ++k) q[k] = 0.f;

            if (n < N_ATOMS) {
                const int start = offs[n];
                const int dc = deg[n];
                if (dc > 0) {
                    int src = ssrc[start], e = seid[start];
                    float v = 0.f;
                    if (l < 32)      v = h_in[src * D + l];
                    else if (l < 48) v = bond[e * BD + (l - 32)];
                    for (int p = 0; p < dc; ++p) {
                        float v2 = 0.f;
                        if (p + 1 < dc) {   // prefetch next edge
                            int s2 = ssrc[start + p + 1];
                            int e2 = seid[start + p + 1];
                            if (l < 32)      v2 = h_in[s2 * D + l];
                            else if (l < 48) v2 = bond[e2 * BD + (l - 32)];
                        }
                        float hj = __shfl(v, li);   // h[src][l&31]
#pragma unroll
                        for (int k = 0; k < 8; ++k) {
                            int b = 2 * k + (l >> 5);        // parity-split channels
                            float bb = __shfl(v, 32 + b);    // bond[e][b]
                            q[k] = fmaf(bb, hj, q[k]);
                        }
                        if (l < 32) q[8] += hj;              // channel 16 (Bm), bond==1
                        v = v2;
                    }
                }
            }
#pragma unroll
            for (int k = 0; k < 9; ++k) {
                int s = l + 64 * k;
                if (s < QW) q_lds[r][s] = q[k];
            }
        }
        __syncthreads();

        // ---- phase 2: agg = q_tile @ WT  (+ load h_tile)
        {
            for (int idx = t; idx < TILE * D; idx += 256) {
                int r = idx >> 5, j = idx & 31;
                int n = base + r;
                h_tile[r][j] = (n < N_ATOMS) ? h_in[n * D + j] : 0.f;
            }
            const int i = t & 31;
            const int r0 = (t >> 5) * 2;
            float a0 = 0.f, a1 = 0.f;
#pragma unroll 8
            for (int s = 0; s < QW; ++s) {
                float wv = WT[s * D + i];
                a0 = fmaf(wv, q_lds[r0][s], a0);
                a1 = fmaf(wv, q_lds[r0 + 1][s], a1);
            }
            agg_lds[r0][i] = a0;
            agg_lds[r0 + 1][i] = a1;
        }
        __syncthreads();

        // ---- phase 3: GRU cell for the 16 nodes
        {
            const int r = t >> 4;
            const int n = base + r;
            const int i0 = t & 15;
            if (n < N_ATOMS) {
                const int iA = i0, iB = i0 + 16;
                float aA0 = bih_s[iA], aA1 = bih_s[32 + iA], aA2 = bih_s[64 + iA];
                float aA3 = bhh_s[iA], aA4 = bhh_s[32 + iA], aA5 = bhh_s[64 + iA];
                float aB0 = bih_s[iB], aB1 = bih_s[32 + iB], aB2 = bih_s[64 + iB];
                float aB3 = bhh_s[iB], aB4 = bhh_s[32 + iB], aB5 = bhh_s[64 + iB];
#pragma unroll 4
                for (int j = 0; j < D; ++j) {
                    float xj = agg_lds[r][j];
                    float hj = h_tile[r][j];
                    aA0 = fmaf(Wih_s[iA][j],      xj, aA0);
                    aA1 = fmaf(Wih_s[32 + iA][j], xj, aA1);
                    aA2 = fmaf(Wih_s[64 + iA][j], xj, aA2);
                    aA3 = fmaf(Whh_s[iA][j],      hj, aA3);
                    aA4 = fmaf(Whh_s[32 + iA][j], hj, aA4);
                    aA5 = fmaf(Whh_s[64 + iA][j], hj, aA5);
                    aB0 = fmaf(Wih_s[iB][j],      xj, aB0);
                    aB1 = fmaf(Wih_s[32 + iB][j], xj, aB1);
                    aB2 = fmaf(Wih_s[64 + iB][j], xj, aB2);
                    aB3 = fmaf(Whh_s[iB][j],      hj, aB3);
                    aB4 = fmaf(Whh_s[32 + iB][j], hj, aB4);
                    aB5 = fmaf(Whh_s[64 + iB][j], hj, aB5);
                }
                float rA = sigmoidf_(aA0 + aA3);
                float zA = sigmoidf_(aA1 + aA4);
                float nA = tanhf(aA2 + rA * aA5);
                h_out[n * D + iA] = (1.f - zA) * nA + zA * h_tile[r][iA];
                float rB = sigmoidf_(aB0 + aB3);
                float zB = sigmoidf_(aB1 + aB4);
                float nB = tanhf(aB2 + rB * aB5);
                h_out[n * D + iB] = (1.f - zB) * nB + zB * h_tile[r][iB];
            }
        }
        __syncthreads();   // protect agg_lds/h_tile before next tile's overwrite
    }
}

// ---------- launch ----------
extern "C" void kernel_launch(void* const* d_in, const int* in_sizes, int n_in,
                              void* d_out, int out_size, void* d_ws, size_t ws_size,
                              hipStream_t stream) {
    const float* atom = (const float*)d_in[0];
    const float* bond = (const float*)d_in[1];
    const int*   pair = (const int*)d_in[2];
    const float* kern = (const float*)d_in[3];
    const float* bias = (const float*)d_in[4];
    const float* Wih  = (const float*)d_in[5];
    const float* Whh  = (const float*)d_in[6];
    const float* bih  = (const float*)d_in[7];
    const float* bhh  = (const float*)d_in[8];
    float* out = (float*)d_out;

    char* w = (char*)d_ws;
    auto alloc = [&](size_t bytes) {
        char* p = w;
        w += (bytes + 255) & ~size_t(255);
        return p;
    };
    float* hA     = (float*)alloc((size_t)N_ATOMS * D * 4);
    float* WT     = (float*)alloc((size_t)NCH * D * D * 4);
    int*   deg    = (int*)alloc((size_t)N_ATOMS * 4);
    int*   offs   = (int*)alloc((size_t)N_ATOMS * 4);
    int*   cursor = (int*)alloc((size_t)N_ATOMS * 4);
    int*   bsums  = (int*)alloc(256 * 4);
    int*   boffs  = (int*)alloc(256 * 4);
    int*   ssrc   = (int*)alloc((size_t)E_EDGES * 4);
    int*   seid   = (int*)alloc((size_t)E_EDGES * 4);

    hipMemsetAsync(deg, 0, (size_t)N_ATOMS * 4, stream);
    hipMemsetAsync(cursor, 0, (size_t)N_ATOMS * 4, stream);

    k_build_wt<<<(NCH * D * D + 255) / 256, 256, 0, stream>>>(kern, bias, WT);
    k_hist<<<(E_EDGES + 255) / 256, 256, 0, stream>>>(pair, deg);
    k_scan1<<<SCAN_BLOCKS, 256, 0, stream>>>(deg, offs, bsums);
    k_scan2<<<1, 256, 0, stream>>>(bsums, boffs, SCAN_BLOCKS);
    k_scan3<<<SCAN_BLOCKS, 256, 0, stream>>>(offs, boffs);
    k_scatter<<<(E_EDGES + 255) / 256, 256, 0, stream>>>(pair, offs, cursor, ssrc, seid);

    // 4 message-passing + GRU steps, ping-pong h between hA and d_out
    k_step<<<512, 256, 0, stream>>>(atom, hA, bond, WT, offs, deg, ssrc, seid,
                                    Wih, Whh, bih, bhh);
    k_step<<<512, 256, 0, stream>>>(hA, out, bond, WT, offs, deg, ssrc, seid,
                                    Wih, Whh, bih, bhh);
    k_step<<<512, 256, 0, stream>>>(out, hA, bond, WT, offs, deg, ssrc, seid,
                                    Wih, Whh, bih, bhh);
    k_step<<<512, 256, 0, stream>>>(hA, out, bond, WT, offs, deg, ssrc, seid,
                                    Wih, Whh, bih, bhh);
}